// Round 3
// baseline (149.327 us; speedup 1.0000x reference)
//
#include <hip/hip_runtime.h>
#include <hip/hip_fp16.h>
#include <stdint.h>

#define I_DIM 2048
#define O_DIM 2048
#define B_DIM 4096
#define KOUT 16

typedef int i32x4 __attribute__((ext_vector_type(4)));
typedef int i32x16 __attribute__((ext_vector_type(16)));
typedef float f32x4 __attribute__((ext_vector_type(4)));
typedef float f32x16 __attribute__((ext_vector_type(16)));
typedef _Float16 f16x8 __attribute__((ext_vector_type(8)));

#define TO_LDS(p) ((__attribute__((address_space(3))) void*)(p))
#define TO_GLB(p) ((const __attribute__((address_space(1))) void*)(p))

// ---------------- Stage 1: column absmax partials (no atomics, no memset) ----------------
__global__ void colmax_kernel(const float* __restrict__ W, float* __restrict__ cmp) {
  int j = blockIdx.x * 256 + threadIdx.x;       // column
  int i0 = blockIdx.y * 64;                     // row chunk
  float m = 0.0f;
  const float* p = W + (size_t)i0 * I_DIM + j;
#pragma unroll 8
  for (int i = 0; i < 64; ++i)
    m = fmaxf(m, fabsf(p[(size_t)i * I_DIM]));
  cmp[blockIdx.y * I_DIM + j] = m;              // partials [32][2048]
}

// ---------------- Stage 2: reduce partials + top-16 + keep mask ----------------
__global__ void topk_kernel(const float* __restrict__ cmp, int* __restrict__ idx,
                            float* __restrict__ keep) {
  int t = threadIdx.x;                          // thread t owns cols {t, t+256, ...}
  float v[8];
#pragma unroll
  for (int u = 0; u < 8; ++u) v[u] = 0.0f;
  for (int rc = 0; rc < 32; ++rc) {
    const float* row = cmp + rc * I_DIM;
#pragma unroll
    for (int u = 0; u < 8; ++u) v[u] = fmaxf(v[u], row[u * 256 + t]);
  }
  for (int j = t; j < I_DIM; j += 256) keep[j] = 1.0f;
  __shared__ float wm_[4];
  __shared__ int wi_[4];
  __shared__ int sel;
  for (int k = 0; k < KOUT; ++k) {
    float m = v[0]; int mi = 0;
#pragma unroll
    for (int u = 1; u < 8; ++u) if (v[u] > m) { m = v[u]; mi = u; }
    int gi = mi * 256 + t;
#pragma unroll
    for (int s = 32; s; s >>= 1) {
      float om = __shfl_down(m, s);
      int oi = __shfl_down(gi, s);
      if (om > m) { m = om; gi = oi; }
    }
    if ((t & 63) == 0) { wm_[t >> 6] = m; wi_[t >> 6] = gi; }
    __syncthreads();
    if (t == 0) {
      float bm = wm_[0]; int bi = wi_[0];
      for (int w2 = 1; w2 < 4; ++w2) if (wm_[w2] > bm) { bm = wm_[w2]; bi = wi_[w2]; }
      idx[k] = bi; keep[bi] = 0.0f; sel = bi;
    }
    __syncthreads();
    if (t == (sel & 255)) v[sel >> 8] = -1.0f;
  }
}

// ---------------- Stage 3: quantize W rows and X rows (merged) ----------------
__global__ __launch_bounds__(256) void quant_kernel(
    const float* __restrict__ X, const float* __restrict__ W,
    const float* __restrict__ keep, const int* __restrict__ idx,
    signed char* __restrict__ xq, signed char* __restrict__ wq,
    float* __restrict__ xmax, float* __restrict__ wmax,
    _Float16* __restrict__ xunqh,   // [B][16] halves
    _Float16* __restrict__ wunqh) { // [O][16] halves
  int b = blockIdx.x;
  int t = threadIdx.x;
  bool isW = b < O_DIM;
  int r = isW ? b : (b - O_DIM);
  const float* src = isW ? (W + (size_t)r * I_DIM) : (X + (size_t)r * I_DIM);
  const float4* s4 = (const float4*)src;
  const float4* k4 = (const float4*)keep;
  float4 v0 = s4[t], v1 = s4[t + 256];
  float4 k0 = k4[t], k1 = k4[t + 256];
  v0.x *= k0.x; v0.y *= k0.y; v0.z *= k0.z; v0.w *= k0.w;
  v1.x *= k1.x; v1.y *= k1.y; v1.z *= k1.z; v1.w *= k1.w;
  float m = fmaxf(fmaxf(fmaxf(fabsf(v0.x), fabsf(v0.y)), fmaxf(fabsf(v0.z), fabsf(v0.w))),
                  fmaxf(fmaxf(fabsf(v1.x), fabsf(v1.y)), fmaxf(fabsf(v1.z), fabsf(v1.w))));
#pragma unroll
  for (int s = 32; s; s >>= 1) m = fmaxf(m, __shfl_xor(m, s));
  __shared__ float red[4];
  if ((t & 63) == 0) red[t >> 6] = m;
  __syncthreads();
  m = fmaxf(fmaxf(red[0], red[1]), fmaxf(red[2], red[3]));
  float sc = 127.0f / m;                        // match ref: scale first, then mul, then trunc
  unsigned p0 = (unsigned char)(signed char)(int)(v0.x * sc)
              | ((unsigned)(unsigned char)(signed char)(int)(v0.y * sc) << 8)
              | ((unsigned)(unsigned char)(signed char)(int)(v0.z * sc) << 16)
              | ((unsigned)(unsigned char)(signed char)(int)(v0.w * sc) << 24);
  unsigned p1 = (unsigned char)(signed char)(int)(v1.x * sc)
              | ((unsigned)(unsigned char)(signed char)(int)(v1.y * sc) << 8)
              | ((unsigned)(unsigned char)(signed char)(int)(v1.z * sc) << 16)
              | ((unsigned)(unsigned char)(signed char)(int)(v1.w * sc) << 24);
  unsigned* qout = (unsigned*)(isW ? (wq + (size_t)r * I_DIM) : (xq + (size_t)r * I_DIM));
  qout[t] = p0;
  qout[t + 256] = p1;
  if (t == 0) { if (isW) wmax[r] = m; else xmax[r] = m; }
  if (t < KOUT) {
    float ov = src[idx[t]];
    _Float16* u = isW ? (wunqh + (size_t)r * KOUT) : (xunqh + (size_t)r * KOUT);
    u[t] = (_Float16)ov;
  }
}

// ---------------- Stage 4: int8 GEMM (C = Xq * Wq^T), 32x32x32 MFMA, BK=128 ----------------
__global__ __launch_bounds__(256) void gemm_kernel(
    const signed char* __restrict__ Aq,   // M x K (x_q)
    const signed char* __restrict__ Bq,   // N x K (w_q)
    const float* __restrict__ xmaxg,      // M
    const float* __restrict__ wmaxg,      // N
    const _Float16* __restrict__ xunqh,   // M x 16
    const _Float16* __restrict__ wunqh,   // N x 16
    const float* __restrict__ biasg,      // N
    float* __restrict__ out) {            // M x N
  constexpr int N = O_DIM, K = I_DIM;
  __shared__ __align__(16) signed char smem[32768];
  signed char* As = smem;                 // 128 rows x 128 B (chunk-XOR-swizzled)
  signed char* Bs = smem + 16384;

  const int tid = threadIdx.x;
  const int lane = tid & 63;
  const int wave = tid >> 6;
  const int h = lane >> 5;                // K-half selector for 32x32 frags
  const int ln31 = lane & 31;
  const int wm = (wave & 1) * 64;
  const int wn = (wave >> 1) * 64;
  const int m0 = blockIdx.y * 128;
  const int n0 = blockIdx.x * 128;

  // staging: shot s, wave w covers flat 16B-slots [(s*4+w)*64 .. +64)
  // LDS slot (row r, chunk c) holds global chunk c ^ (r & 7)
  const signed char* srcA[4];
  const signed char* srcB[4];
#pragma unroll
  for (int s = 0; s < 4; ++s) {
    int f = (s * 4 + wave) * 64 + lane;
    int r = f >> 3;
    int g = (f & 7) ^ (r & 7);
    srcA[s] = Aq + (size_t)(m0 + r) * K + g * 16;
    srcB[s] = Bq + (size_t)(n0 + r) * K + g * 16;
  }

  // fragment read bases: row rA = wm + ln31 (+32), phys chunk = (st*2+h) ^ (row&7)
  const int rA0 = wm + ln31, rA1 = rA0 + 32;
  const int rB0 = wn + ln31, rB1 = rB0 + 32;
  const int oA0 = rA0 * 128, sA0 = rA0 & 7;
  const int oA1 = rA1 * 128, sA1 = rA1 & 7;
  const int oB0 = rB0 * 128, sB0 = rB0 & 7;
  const int oB1 = rB1 * 128, sB1 = rB1 & 7;

  // outlier fragments (K=16 exactly -> one 32x32x16 f16 MFMA per tile)
  f16x8 afh[2], bfh[2];
#pragma unroll
  for (int i = 0; i < 2; ++i)
    afh[i] = *(const f16x8*)(xunqh + (size_t)(m0 + wm + i * 32 + ln31) * KOUT + h * 8);
#pragma unroll
  for (int j = 0; j < 2; ++j)
    bfh[j] = *(const f16x8*)(wunqh + (size_t)(n0 + wn + j * 32 + ln31) * KOUT + h * 8);

  i32x16 acc[2][2] = {};

  for (int kt = 0; kt < K; kt += 128) {
#pragma unroll
    for (int s = 0; s < 4; ++s) {
      __builtin_amdgcn_global_load_lds(TO_GLB(srcA[s] + kt), TO_LDS(As + (s * 4 + wave) * 1024), 16, 0, 0);
      __builtin_amdgcn_global_load_lds(TO_GLB(srcB[s] + kt), TO_LDS(Bs + (s * 4 + wave) * 1024), 16, 0, 0);
    }
    __syncthreads();
#pragma unroll
    for (int st = 0; st < 4; ++st) {
      int lc = st * 2 + h;
      i32x4 a0 = *(const i32x4*)(As + oA0 + ((lc ^ sA0) << 4));
      i32x4 a1 = *(const i32x4*)(As + oA1 + ((lc ^ sA1) << 4));
      i32x4 b0 = *(const i32x4*)(Bs + oB0 + ((lc ^ sB0) << 4));
      i32x4 b1 = *(const i32x4*)(Bs + oB1 + ((lc ^ sB1) << 4));
      acc[0][0] = __builtin_amdgcn_mfma_i32_32x32x32_i8(a0, b0, acc[0][0], 0, 0, 0);
      acc[0][1] = __builtin_amdgcn_mfma_i32_32x32x32_i8(a0, b1, acc[0][1], 0, 0, 0);
      acc[1][0] = __builtin_amdgcn_mfma_i32_32x32x32_i8(a1, b0, acc[1][0], 0, 0, 0);
      acc[1][1] = __builtin_amdgcn_mfma_i32_32x32x32_i8(a1, b1, acc[1][1], 0, 0, 0);
    }
    __syncthreads();
  }

  // ---- epilogue: dequant + fp16 round-trip + rank-16 outlier MFMA + bias ----
  const float recip = 1.0f / 16129.0f;   // mult instead of IEEE div: <=1.5ulp f32 drift
                                         // before fp16 RN truncation -> ~2e-3 output drift
#pragma unroll
  for (int i = 0; i < 2; ++i) {
#pragma unroll
    for (int j = 0; j < 2; ++j) {
      int col = n0 + wn + j * 32 + ln31;
      float wmv = wmaxg[col];
      float bv = biasg[col];
      f32x16 c;
#pragma unroll
      for (int g = 0; g < 4; ++g) {
        int rbase = m0 + wm + i * 32 + g * 8 + h * 4;
        f32x4 xmv = *(const f32x4*)(xmaxg + rbase);
#pragma unroll
        for (int r = 0; r < 4; ++r) {
          float v = (float)acc[i][j][g * 4 + r] * recip;
          v = __half2float(__float2half(v));        // fp16 round-trip (RN), matches ref
          c[g * 4 + r] = v * (xmv[r] * wmv) + bv;
        }
      }
      c = __builtin_amdgcn_mfma_f32_32x32x16_f16(afh[i], bfh[j], c, 0, 0, 0);
#pragma unroll
      for (int g = 0; g < 4; ++g) {
        int rbase = m0 + wm + i * 32 + g * 8 + h * 4;
#pragma unroll
        for (int r = 0; r < 4; ++r)
          out[(size_t)(rbase + r) * N + col] = c[g * 4 + r];
      }
    }
  }
}

extern "C" void kernel_launch(void* const* d_in, const int* in_sizes, int n_in,
                              void* d_out, int out_size, void* d_ws, size_t ws_size,
                              hipStream_t stream) {
  const float* x    = (const float*)d_in[0];   // 4096 x 2048
  const float* w    = (const float*)d_in[1];   // 2048 x 2048
  const float* bias = (const float*)d_in[2];   // 2048
  float* out = (float*)d_out;
  char* ws = (char*)d_ws;

  float* cm_part   = (float*)(ws + 0);           // 32*2048*4 = 256 KB
  int* idx         = (int*)(ws + 262144);        // 64 B
  float* keep      = (float*)(ws + 262272);      // 8 KB
  float* w_max     = (float*)(ws + 270464);      // 8 KB
  float* x_max     = (float*)(ws + 278656);      // 16 KB
  _Float16* x_unqh = (_Float16*)(ws + 295040);   // 4096*16*2 = 128 KB
  _Float16* w_unqh = (_Float16*)(ws + 426112);   // 2048*16*2 = 64 KB
  signed char* w_q = (signed char*)(ws + 491648);   // 4 MB
  signed char* x_q = (signed char*)(ws + 4685952);  // 8 MB (total ~12.6 MB)

  colmax_kernel<<<dim3(8, 32), 256, 0, stream>>>(w, cm_part);
  topk_kernel<<<1, 256, 0, stream>>>(cm_part, idx, keep);
  quant_kernel<<<O_DIM + B_DIM, 256, 0, stream>>>(x, w, keep, idx, x_q, w_q,
                                                  x_max, w_max, x_unqh, w_unqh);
  gemm_kernel<<<dim3(O_DIM / 128, B_DIM / 128), 256, 0, stream>>>(
      x_q, w_q, x_max, w_max, x_unqh, w_unqh, bias, out);
}